// Round 2
// baseline (3973.244 us; speedup 1.0000x reference)
//
#include <hip/hip_runtime.h>

// Problem constants (reference: B=4,H=16,S=2048,D=64, fp32, mask int32 (jnp.bool_ pushed as int))
#define BATCH 4
#define HEADS 16
#define SEQ 2048
#define DIM 64
#define BHN (BATCH*HEADS)          // 64
#define QBLK 16                    // q rows per workgroup
#define KTILE 64                   // k columns per tile
#define NTILES (SEQ/KTILE)         // 32
#define THREADS 512                // 8 waves
#define SCALE 0.125f               // 1/sqrt(64)
#define LOG2E 1.4426950408889634f

__global__ __launch_bounds__(THREADS)
void sdpa_kernel(const float* __restrict__ Q, const float* __restrict__ K,
                 const float* __restrict__ V, const int* __restrict__ mask,
                 float* __restrict__ ctx_out, float* __restrict__ prob_out) {
    __shared__ float Qs[QBLK][DIM];        // 4 KB
    __shared__ float Ks[KTILE * DIM];      // 16 KB, XOR-swizzled (see below)
    __shared__ float Vs[KTILE][DIM];       // 16 KB, linear
    __shared__ float Ps[QBLK][KTILE];      // 4 KB

    const int bid  = blockIdx.x;
    const int bh   = bid >> 7;             // SEQ/QBLK = 128 q-blocks per head
    const int q0   = (bid & 127) * QBLK;
    const int t    = threadIdx.x;
    const int lane = t & 63;
    const int wave = t >> 6;               // 0..7

    const size_t bh_off = (size_t)bh * SEQ * DIM;
    const float* Qb = Q + bh_off;
    const float* Kb = K + bh_off;
    const float* Vb = V + bh_off;
    const int* Mb = mask + (size_t)bh * SEQ * SEQ;

    // ---- stage Q block: 16 rows x 64 floats = 1024 floats ----
    if (t < 256) {
        int r  = t >> 4;
        int d0 = (t & 15) * 4;
        float4 v = *(const float4*)(Qb + (size_t)(q0 + r) * DIM + d0);
        *(float4*)(&Qs[r][d0]) = v;
    }
    __syncthreads();

    // Each wave owns 2 q rows; lane owns k = tile*64 + lane.
    const int r0 = wave * 2;
    const int r1 = r0 + 1;

    float s0[NTILES];  // scores (later probs) for row r0, this lane's k
    float s1[NTILES];

    // =================== Phase A: scores = QK^T * scale, masked ===================
    const int sx = (lane & 7) << 2;        // read-side swizzle for this lane's k-row
    #pragma unroll
    for (int tile = 0; tile < NTILES; ++tile) {
        // stage K tile (4096 floats, 2 float4 per thread), XOR-swizzled:
        // element (k,d) stored at float index k*64 + (d ^ ((k&7)<<2))
        #pragma unroll
        for (int i = 0; i < 2; ++i) {
            int e  = (i * THREADS + t) * 4;            // 0..4095
            int k  = e >> 6;
            int d0 = e & 63;
            float4 v = *(const float4*)(Kb + (size_t)tile * (KTILE*DIM) + e);
            *(float4*)(&Ks[k * 64 + (d0 ^ ((k & 7) << 2))]) = v;
        }
        __syncthreads();

        float acc0 = 0.f, acc1 = 0.f;
        const float* kr = &Ks[lane * 64];
        #pragma unroll 4
        for (int d0 = 0; d0 < 64; d0 += 4) {
            float4 kv = *(const float4*)(kr + (d0 ^ sx));     // conflict-free b128
            float4 qa = *(const float4*)(&Qs[r0][d0]);        // wave-broadcast
            float4 qb = *(const float4*)(&Qs[r1][d0]);
            acc0 += qa.x * kv.x + qa.y * kv.y + qa.z * kv.z + qa.w * kv.w;
            acc1 += qb.x * kv.x + qb.y * kv.y + qb.z * kv.z + qb.w * kv.w;
        }

        int kg = tile * KTILE + lane;
        int m0 = Mb[(size_t)(q0 + r0) * SEQ + kg];            // coalesced 256B/row
        int m1 = Mb[(size_t)(q0 + r1) * SEQ + kg];
        s0[tile] = m0 ? -1e9f : acc0 * SCALE;                 // True -> MASK_FILL
        s1[tile] = m1 ? -1e9f : acc1 * SCALE;
        __syncthreads();                                      // Ks reused next tile
    }

    // =================== softmax (per row, distributed across 64 lanes) ===================
    float m0 = -1e30f, m1 = -1e30f;
    #pragma unroll
    for (int j = 0; j < NTILES; ++j) { m0 = fmaxf(m0, s0[j]); m1 = fmaxf(m1, s1[j]); }
    #pragma unroll
    for (int off = 32; off > 0; off >>= 1) {
        m0 = fmaxf(m0, __shfl_xor(m0, off));
        m1 = fmaxf(m1, __shfl_xor(m1, off));
    }
    float sum0 = 0.f, sum1 = 0.f;
    #pragma unroll
    for (int j = 0; j < NTILES; ++j) {
        float p0 = exp2f((s0[j] - m0) * LOG2E);
        float p1 = exp2f((s1[j] - m1) * LOG2E);
        s0[j] = p0; sum0 += p0;
        s1[j] = p1; sum1 += p1;
    }
    #pragma unroll
    for (int off = 32; off > 0; off >>= 1) {
        sum0 += __shfl_xor(sum0, off);
        sum1 += __shfl_xor(sum1, off);
    }
    const float inv0 = 1.0f / sum0;
    const float inv1 = 1.0f / sum1;

    // =================== Phase B: write probs, context = P @ V ===================
    const int pq = t >> 5;          // 0..15 : q row this thread accumulates
    const int pd = (t & 31) * 2;    // d pair
    float cx = 0.f, cy = 0.f;

    float* prob_r0 = prob_out + ((size_t)bh * SEQ + (q0 + r0)) * SEQ;
    float* prob_r1 = prob_out + ((size_t)bh * SEQ + (q0 + r1)) * SEQ;

    #pragma unroll
    for (int tile = 0; tile < NTILES; ++tile) {
        // stage V tile (linear layout)
        #pragma unroll
        for (int i = 0; i < 2; ++i) {
            int e = (i * THREADS + t) * 4;
            *(float4*)(&Vs[0][0] + e) =
                *(const float4*)(Vb + (size_t)tile * (KTILE*DIM) + e);
        }
        // normalized probs -> LDS + global (coalesced 256B per row per wave)
        float p0 = s0[tile] * inv0;
        float p1 = s1[tile] * inv1;
        Ps[r0][lane] = p0;
        Ps[r1][lane] = p1;
        prob_r0[tile * KTILE + lane] = p0;
        prob_r1[tile * KTILE + lane] = p1;
        __syncthreads();

        #pragma unroll 8
        for (int k = 0; k < KTILE; ++k) {
            float p = Ps[pq][k];                        // broadcast
            float2 v = *(const float2*)(&Vs[k][pd]);    // conflict-free
            cx += p * v.x;
            cy += p * v.y;
        }
        __syncthreads();                                // Ps/Vs reused next tile
    }

    float2 cv = make_float2(cx, cy);
    *(float2*)(ctx_out + ((size_t)bh * SEQ + (q0 + pq)) * DIM + pd) = cv;
}

extern "C" void kernel_launch(void* const* d_in, const int* in_sizes, int n_in,
                              void* d_out, int out_size, void* d_ws, size_t ws_size,
                              hipStream_t stream) {
    const float* Q = (const float*)d_in[0];
    const float* K = (const float*)d_in[1];
    const float* V = (const float*)d_in[2];
    const int* mask = (const int*)d_in[3];              // jnp.bool_ pushed as int32
    float* ctx  = (float*)d_out;                        // context first
    float* prob = (float*)d_out + (size_t)BATCH * HEADS * SEQ * DIM; // then attn_prob

    dim3 grid(BHN * (SEQ / QBLK));   // 64 * 128 = 8192
    dim3 block(THREADS);
    sdpa_kernel<<<grid, block, 0, stream>>>(Q, K, V, mask, ctx, prob);
}

// Round 3
// 1220.847 us; speedup vs baseline: 3.2545x; 3.2545x over previous
//
#include <hip/hip_runtime.h>

// B=4,H=16,S=2048,D=64 fp32 SDPA with materialized attn_prob.
// MFMA bf16 path: swapped QK^T (S^T = K*Q^T) so each lane owns ONE q-row.
#define SEQ 2048
#define DIM 64
#define QBLK 16
#define NWAVE 8
#define KPW 256                 // k-columns per wave
#define NCT 16                  // 16-wide column tiles per wave
#define NCHUNK 8                // 32-wide PV chunks per wave
#define THREADS 512
#define SCALE 0.125f            // 1/sqrt(64)
#define LOG2E 1.4426950408889634f

typedef __attribute__((ext_vector_type(4))) float f32x4;
typedef __attribute__((ext_vector_type(8))) __bf16 bf16x8;

static __device__ __forceinline__ __bf16 f2bf(float f) { return (__bf16)f; }

__global__ __launch_bounds__(THREADS)
void sdpa_mfma(const float* __restrict__ Q, const float* __restrict__ K,
               const float* __restrict__ V, const int* __restrict__ mask,
               float* __restrict__ ctx_out, float* __restrict__ prob_out) {
    // wave-private P tile: [wave][q 0..15][k_loc 0..31] bf16 (8 KB total)
    __shared__ __bf16 P_lds[NWAVE][QBLK][32];
    __shared__ float red_m[QBLK][NWAVE];        // row-max exchange
    __shared__ float red_s[QBLK][NWAVE];        // row-sum exchange
    __shared__ float ctx_sm[NWAVE][QBLK * DIM]; // 32 KB ctx reduction

    const int bid  = blockIdx.x;
    const int bh   = bid >> 7;              // 128 q-blocks per (b,h)
    const int q0   = (bid & 127) * QBLK;
    const int t    = threadIdx.x;
    const int lane = t & 63;
    const int w    = t >> 6;                // wave 0..7
    const int g    = lane >> 4;             // 0..3
    const int c    = lane & 15;             // 0..15  (this lane's q-row AND its N-col)

    const size_t bh_off = (size_t)bh * SEQ * DIM;
    const float* Qb = Q + bh_off;
    const float* Kb = K + bh_off;
    const float* Vb = V + bh_off;
    const int*   Mb = mask + (size_t)bh * SEQ * SEQ;
    const int wbase = w * KPW;

    // ---- Q^T B-fragments (B[d][q]: lane holds col q=c, rows d=8g+j), kept in regs ----
    bf16x8 qf[2];
    {
        const float* qr = Qb + (size_t)(q0 + c) * DIM + 8 * g;
        #pragma unroll
        for (int h = 0; h < 2; ++h) {
            f32x4 a = *(const f32x4*)(qr + 32 * h);
            f32x4 b = *(const f32x4*)(qr + 32 * h + 4);
            bf16x8 f;
            f[0]=f2bf(a[0]); f[1]=f2bf(a[1]); f[2]=f2bf(a[2]); f[3]=f2bf(a[3]);
            f[4]=f2bf(b[0]); f[5]=f2bf(b[1]); f[6]=f2bf(b[2]); f[7]=f2bf(b[3]);
            qf[h] = f;
        }
    }

    // =============== QK^T (swapped): per tile, D[k_loc=4g+jr][q=c] ===============
    f32x4 sc[NCT];   // lane's scores: q = c fixed, k = wbase + ct*16 + 4g + jr
    #pragma unroll
    for (int ct = 0; ct < NCT; ++ct) {
        const float* kr = Kb + (size_t)(wbase + ct * 16 + c) * DIM + 8 * g;
        bf16x8 kf[2];
        #pragma unroll
        for (int h = 0; h < 2; ++h) {
            f32x4 a = *(const f32x4*)(kr + 32 * h);
            f32x4 b = *(const f32x4*)(kr + 32 * h + 4);
            bf16x8 f;
            f[0]=f2bf(a[0]); f[1]=f2bf(a[1]); f[2]=f2bf(a[2]); f[3]=f2bf(a[3]);
            f[4]=f2bf(b[0]); f[5]=f2bf(b[1]); f[6]=f2bf(b[2]); f[7]=f2bf(b[3]);
            kf[h] = f;
        }
        f32x4 acc = {0.f, 0.f, 0.f, 0.f};
        acc = __builtin_amdgcn_mfma_f32_16x16x32_bf16(kf[0], qf[0], acc, 0, 0, 0);
        acc = __builtin_amdgcn_mfma_f32_16x16x32_bf16(kf[1], qf[1], acc, 0, 0, 0);

        int4 m = *(const int4*)(Mb + (size_t)(q0 + c) * SEQ + wbase + ct * 16 + 4 * g);
        f32x4 s;
        s[0] = m.x ? -1e9f : acc[0] * SCALE;
        s[1] = m.y ? -1e9f : acc[1] * SCALE;
        s[2] = m.z ? -1e9f : acc[2] * SCALE;
        s[3] = m.w ? -1e9f : acc[3] * SCALE;
        sc[ct] = s;
    }

    // =============== softmax over the full row (lane owns row q=c) ===============
    float mx = -3e38f;
    #pragma unroll
    for (int ct = 0; ct < NCT; ++ct)
        mx = fmaxf(mx, fmaxf(fmaxf(sc[ct][0], sc[ct][1]), fmaxf(sc[ct][2], sc[ct][3])));
    mx = fmaxf(mx, __shfl_xor(mx, 16));
    mx = fmaxf(mx, __shfl_xor(mx, 32));
    if (g == 0) red_m[c][w] = mx;
    __syncthreads();
    float M = red_m[c][0];
    #pragma unroll
    for (int i = 1; i < NWAVE; ++i) M = fmaxf(M, red_m[c][i]);

    float sum = 0.f;
    #pragma unroll
    for (int ct = 0; ct < NCT; ++ct) {
        f32x4 s = sc[ct];
        s[0] = exp2f((s[0] - M) * LOG2E);
        s[1] = exp2f((s[1] - M) * LOG2E);
        s[2] = exp2f((s[2] - M) * LOG2E);
        s[3] = exp2f((s[3] - M) * LOG2E);
        sum += (s[0] + s[1]) + (s[2] + s[3]);
        sc[ct] = s;
    }
    sum += __shfl_xor(sum, 16);
    sum += __shfl_xor(sum, 32);
    if (g == 0) red_s[c][w] = sum;
    __syncthreads();
    float S = 0.f;
    #pragma unroll
    for (int i = 0; i < NWAVE; ++i) S += red_s[c][i];
    const float inv = 1.0f / S;

    // =============== normalize + write prob (float4, 64B-dense per row) ===============
    float* prow = prob_out + ((size_t)bh * SEQ + (q0 + c)) * SEQ + wbase;
    #pragma unroll
    for (int ct = 0; ct < NCT; ++ct) {
        f32x4 p = sc[ct];
        p[0] *= inv; p[1] *= inv; p[2] *= inv; p[3] *= inv;
        sc[ct] = p;
        *(f32x4*)(prow + ct * 16 + 4 * g) = p;
    }

    // =============== PV: ctx[q][dv] += P[q][k] V[k][dv], wave-private ===============
    f32x4 cacc[4];
    #pragma unroll
    for (int nt = 0; nt < 4; ++nt) cacc[nt] = (f32x4){0.f, 0.f, 0.f, 0.f};

    #pragma unroll
    for (int cc = 0; cc < NCHUNK; ++cc) {
        // pack this chunk's P (2 tiles) into wave-private LDS [q][k_loc] bf16
        {
            f32x4 pa = sc[2 * cc], pb = sc[2 * cc + 1];
            __bf16* row = &P_lds[w][c][0];
            row[4 * g + 0]      = f2bf(pa[0]);
            row[4 * g + 1]      = f2bf(pa[1]);
            row[4 * g + 2]      = f2bf(pa[2]);
            row[4 * g + 3]      = f2bf(pa[3]);
            row[16 + 4 * g + 0] = f2bf(pb[0]);
            row[16 + 4 * g + 1] = f2bf(pb[1]);
            row[16 + 4 * g + 2] = f2bf(pb[2]);
            row[16 + 4 * g + 3] = f2bf(pb[3]);
        }
        // A-frag: lane holds P[q=c][k=8g+j] -> one 16B LDS read (compiler inserts wait)
        bf16x8 pf = *(const bf16x8*)&P_lds[w][c][8 * g];

        // B-frags: V[kbase+8g+j][nt*16+c], coalesced dword loads (4x64B lines/instr)
        const float* vbase = Vb + (size_t)(wbase + cc * 32 + 8 * g) * DIM + c;
        #pragma unroll
        for (int nt = 0; nt < 4; ++nt) {
            bf16x8 vf;
            #pragma unroll
            for (int j = 0; j < 8; ++j)
                vf[j] = f2bf(vbase[(size_t)j * DIM + nt * 16]);
            cacc[nt] = __builtin_amdgcn_mfma_f32_16x16x32_bf16(pf, vf, cacc[nt], 0, 0, 0);
        }
    }

    // =============== cross-wave ctx reduction ===============
    #pragma unroll
    for (int nt = 0; nt < 4; ++nt)
        #pragma unroll
        for (int jr = 0; jr < 4; ++jr)
            ctx_sm[w][(4 * g + jr) * DIM + nt * 16 + c] = cacc[nt][jr];
    __syncthreads();
    {
        int e = t * 2;
        float2 a = make_float2(0.f, 0.f);
        #pragma unroll
        for (int i = 0; i < NWAVE; ++i) {
            float2 v = *(const float2*)&ctx_sm[i][e];
            a.x += v.x; a.y += v.y;
        }
        *(float2*)(ctx_out + ((size_t)bh * SEQ + q0) * DIM + e) = a;
    }
}

extern "C" void kernel_launch(void* const* d_in, const int* in_sizes, int n_in,
                              void* d_out, int out_size, void* d_ws, size_t ws_size,
                              hipStream_t stream) {
    const float* Q = (const float*)d_in[0];
    const float* K = (const float*)d_in[1];
    const float* V = (const float*)d_in[2];
    const int* mask = (const int*)d_in[3];              // jnp.bool_ pushed as int32
    float* ctx  = (float*)d_out;
    float* prob = (float*)d_out + (size_t)4 * 16 * SEQ * DIM;

    dim3 grid(64 * (SEQ / QBLK));   // 64 bh * 128 q-blocks = 8192
    dim3 block(THREADS);
    sdpa_mfma<<<grid, block, 0, stream>>>(Q, K, V, mask, ctx, prob);
}

// Round 7
// 1209.620 us; speedup vs baseline: 3.2847x; 1.0093x over previous
//
#include <hip/hip_runtime.h>
#include <stdint.h>

// B=4,H=16,S=2048,D=64 fp32 SDPA with materialized attn_prob.
// Swapped QK^T MFMA (lane owns one q-row); P via padded-LDS round-trip (r3-verified);
// V via vectorized LDS staging + compiler-visible scalar column reads (correct-by-construction).
#define SEQ 2048
#define DIM 64
#define QBLK 16
#define NWAVE 8
#define KPW 256                 // k-columns per wave
#define NCT 16                  // 16-wide tiles per wave (QK^T)
#define NCHUNK 8                // 32-wide PV chunks per wave
#define THREADS 512
#define SCALE 0.125f
#define LOG2E 1.4426950408889634f
#define PSTR 40                 // plds row stride in bf16 (80 B, conflict-free b128)
#define VPAD 20                 // vbuf row stride in bf16 (40 B = 10 dwords -> 2-way reads)

typedef __attribute__((ext_vector_type(4))) float f32x4;
typedef __attribute__((ext_vector_type(8))) __bf16 bf16x8;

static __device__ __forceinline__ unsigned int bfbits(float x) {
    union { __bf16 b; unsigned short u; } cv; cv.b = (__bf16)x; return (unsigned int)cv.u;
}

struct WaveBuf {
    union {
        __bf16 vbuf[4][32][VPAD];    // 5120 B: V chunk, [nt][k][c] padded
        float  ctx[QBLK * DIM];      // 4096 B: ctx partial (same region, used after PV)
    };
};

struct SharedT {
    WaveBuf sw[NWAVE];               // 40960 B
    __bf16 plds[NWAVE][QBLK][PSTR];  // 10240 B: P round-trip, padded stride
    float red_m[QBLK][NWAVE];
    float red_s[QBLK][NWAVE];
};

__global__ __launch_bounds__(THREADS)
void sdpa_mfma5(const float* __restrict__ Q, const float* __restrict__ K,
                const float* __restrict__ V, const int* __restrict__ mask,
                float* __restrict__ ctx_out, float* __restrict__ prob_out) {
    __shared__ SharedT su;

    const int bid  = blockIdx.x;
    const int bh   = bid >> 7;
    const int q0   = (bid & 127) * QBLK;
    const int t    = threadIdx.x;
    const int lane = t & 63;
    const int w    = t >> 6;
    const int g    = lane >> 4;          // 0..3
    const int c    = lane & 15;          // lane's q-row (and N-col)

    const size_t bh_off = (size_t)bh * SEQ * DIM;
    const float* Qb = Q + bh_off;
    const float* Kb = K + bh_off;
    const float* Vb = V + bh_off;
    const int*   Mb = mask + (size_t)bh * SEQ * SEQ;
    const int wbase = w * KPW;

    // ---- Q^T B-fragments, from global, kept in regs ----
    bf16x8 qf[2];
    {
        const float* qr = Qb + (size_t)(q0 + c) * DIM + 8 * g;
        #pragma unroll
        for (int h = 0; h < 2; ++h) {
            f32x4 a = *(const f32x4*)(qr + 32 * h);
            f32x4 b = *(const f32x4*)(qr + 32 * h + 4);
            bf16x8 f;
            f[0]=(__bf16)a[0]; f[1]=(__bf16)a[1]; f[2]=(__bf16)a[2]; f[3]=(__bf16)a[3];
            f[4]=(__bf16)b[0]; f[5]=(__bf16)b[1]; f[6]=(__bf16)b[2]; f[7]=(__bf16)b[3];
            qf[h] = f;
        }
    }

    // =============== QK^T (r3-verified simple loop) ===============
    f32x4 sc[NCT];
    #pragma unroll
    for (int ct = 0; ct < NCT; ++ct) {
        const float* kr = Kb + (size_t)(wbase + ct * 16 + c) * DIM + 8 * g;
        bf16x8 kf[2];
        #pragma unroll
        for (int h = 0; h < 2; ++h) {
            f32x4 a = *(const f32x4*)(kr + 32 * h);
            f32x4 b = *(const f32x4*)(kr + 32 * h + 4);
            bf16x8 f;
            f[0]=(__bf16)a[0]; f[1]=(__bf16)a[1]; f[2]=(__bf16)a[2]; f[3]=(__bf16)a[3];
            f[4]=(__bf16)b[0]; f[5]=(__bf16)b[1]; f[6]=(__bf16)b[2]; f[7]=(__bf16)b[3];
            kf[h] = f;
        }
        f32x4 acc = {0.f, 0.f, 0.f, 0.f};
        acc = __builtin_amdgcn_mfma_f32_16x16x32_bf16(kf[0], qf[0], acc, 0, 0, 0);
        acc = __builtin_amdgcn_mfma_f32_16x16x32_bf16(kf[1], qf[1], acc, 0, 0, 0);

        int4 m = *(const int4*)(Mb + (size_t)(q0 + c) * SEQ + wbase + ct * 16 + 4 * g);
        f32x4 s;
        s[0] = m.x ? -1e9f : acc[0] * SCALE;
        s[1] = m.y ? -1e9f : acc[1] * SCALE;
        s[2] = m.z ? -1e9f : acc[2] * SCALE;
        s[3] = m.w ? -1e9f : acc[3] * SCALE;
        sc[ct] = s;
    }

    // =============== softmax (lane owns row q=c) ===============
    float mx = -3e38f;
    #pragma unroll
    for (int ct = 0; ct < NCT; ++ct)
        mx = fmaxf(mx, fmaxf(fmaxf(sc[ct][0], sc[ct][1]), fmaxf(sc[ct][2], sc[ct][3])));
    mx = fmaxf(mx, __shfl_xor(mx, 16));
    mx = fmaxf(mx, __shfl_xor(mx, 32));
    if (g == 0) su.red_m[c][w] = mx;
    __syncthreads();
    float M = su.red_m[c][0];
    #pragma unroll
    for (int i = 1; i < NWAVE; ++i) M = fmaxf(M, su.red_m[c][i]);

    float sum = 0.f;
    #pragma unroll
    for (int ct = 0; ct < NCT; ++ct) {
        f32x4 s = sc[ct];
        s[0] = exp2f((s[0] - M) * LOG2E);
        s[1] = exp2f((s[1] - M) * LOG2E);
        s[2] = exp2f((s[2] - M) * LOG2E);
        s[3] = exp2f((s[3] - M) * LOG2E);
        sum += (s[0] + s[1]) + (s[2] + s[3]);
        sc[ct] = s;
    }
    sum += __shfl_xor(sum, 16);
    sum += __shfl_xor(sum, 32);
    if (g == 0) su.red_s[c][w] = sum;
    __syncthreads();
    float S = 0.f;
    #pragma unroll
    for (int i = 0; i < NWAVE; ++i) S += su.red_s[c][i];
    const float inv = 1.0f / S;

    // =============== PV + prob write, barrier-free per wave ===============
    f32x4 cacc[4];
    #pragma unroll
    for (int nt = 0; nt < 4; ++nt) cacc[nt] = (f32x4){0.f, 0.f, 0.f, 0.f};

    const int r_st = lane >> 4;              // staging row-within-4 group
    const int c0   = (lane & 15) * 4;        // staging col (global dv)
    const int ntw  = c0 >> 4;                // nt block this lane stages
    const int cw   = c0 & 15;

    float* prow = prob_out + ((size_t)bh * SEQ + (q0 + c)) * SEQ + wbase;

    #pragma unroll
    for (int cc = 0; cc < NCHUNK; ++cc) {
        // issue first-half V loads early
        const float* vsrc = Vb + (size_t)(wbase + cc * 32 + r_st) * DIM + c0;
        f32x4 vraw[4];
        #pragma unroll
        for (int i = 0; i < 4; ++i)
            vraw[i] = *(const f32x4*)(vsrc + (size_t)(4 * i) * DIM);

        // prob normalize + write (overlaps V-load latency)
        f32x4 p0 = sc[2 * cc], p1 = sc[2 * cc + 1];
        p0[0]*=inv; p0[1]*=inv; p0[2]*=inv; p0[3]*=inv;
        p1[0]*=inv; p1[1]*=inv; p1[2]*=inv; p1[3]*=inv;
        *(f32x4*)(prow + 32 * cc + 4 * g)      = p0;
        *(f32x4*)(prow + 32 * cc + 16 + 4 * g) = p1;

        // P -> padded LDS (r3 mechanism), then b128 A-frag read
        {
            ushort4 pk;
            pk.x = (unsigned short)bfbits(p0[0]);
            pk.y = (unsigned short)bfbits(p0[1]);
            pk.z = (unsigned short)bfbits(p0[2]);
            pk.w = (unsigned short)bfbits(p0[3]);
            *(ushort4*)&su.plds[w][c][4 * g] = pk;
            pk.x = (unsigned short)bfbits(p1[0]);
            pk.y = (unsigned short)bfbits(p1[1]);
            pk.z = (unsigned short)bfbits(p1[2]);
            pk.w = (unsigned short)bfbits(p1[3]);
            *(ushort4*)&su.plds[w][c][16 + 4 * g] = pk;
        }
        bf16x8 pf = *(const bf16x8*)&su.plds[w][c][8 * g];

        // stage V: first half (rows 0..15), then second half (rows 16..31)
        #pragma unroll
        for (int i = 0; i < 4; ++i) {
            ushort4 pk;
            pk.x = (unsigned short)bfbits(vraw[i][0]);
            pk.y = (unsigned short)bfbits(vraw[i][1]);
            pk.z = (unsigned short)bfbits(vraw[i][2]);
            pk.w = (unsigned short)bfbits(vraw[i][3]);
            *(ushort4*)&su.sw[w].vbuf[ntw][4 * i + r_st][cw] = pk;
        }
        #pragma unroll
        for (int i = 0; i < 4; ++i)
            vraw[i] = *(const f32x4*)(vsrc + (size_t)(16 + 4 * i) * DIM);
        #pragma unroll
        for (int i = 0; i < 4; ++i) {
            ushort4 pk;
            pk.x = (unsigned short)bfbits(vraw[i][0]);
            pk.y = (unsigned short)bfbits(vraw[i][1]);
            pk.z = (unsigned short)bfbits(vraw[i][2]);
            pk.w = (unsigned short)bfbits(vraw[i][3]);
            *(ushort4*)&su.sw[w].vbuf[ntw][16 + 4 * i + r_st][cw] = pk;
        }

        // B-frags: compiler-visible scalar column reads (2-way banks = free);
        // compiler orders these after the wave's own ds_writes.
        bf16x8 vfr[4];
        #pragma unroll
        for (int nt = 0; nt < 4; ++nt) {
            bf16x8 f;
            #pragma unroll
            for (int j = 0; j < 8; ++j)
                f[j] = su.sw[w].vbuf[nt][8 * g + j][c];
            vfr[nt] = f;
        }

        __builtin_amdgcn_s_setprio(1);
        #pragma unroll
        for (int nt = 0; nt < 4; ++nt)
            cacc[nt] = __builtin_amdgcn_mfma_f32_16x16x32_bf16(pf, vfr[nt], cacc[nt], 0, 0, 0);
        __builtin_amdgcn_s_setprio(0);
    }

    // =============== ctx partials (own region overlays own vbuf) + reduce ===============
    #pragma unroll
    for (int nt = 0; nt < 4; ++nt)
        #pragma unroll
        for (int jr = 0; jr < 4; ++jr)
            su.sw[w].ctx[(4 * g + jr) * DIM + nt * 16 + c] = cacc[nt][jr];
    __syncthreads();
    {
        int e = t * 2;
        float2 a = make_float2(0.f, 0.f);
        #pragma unroll
        for (int i = 0; i < NWAVE; ++i) {
            float2 v = *(const float2*)&su.sw[i].ctx[e];
            a.x += v.x; a.y += v.y;
        }
        *(float2*)(ctx_out + ((size_t)bh * SEQ + q0) * DIM + e) = a;
    }
}

extern "C" void kernel_launch(void* const* d_in, const int* in_sizes, int n_in,
                              void* d_out, int out_size, void* d_ws, size_t ws_size,
                              hipStream_t stream) {
    const float* Q = (const float*)d_in[0];
    const float* K = (const float*)d_in[1];
    const float* V = (const float*)d_in[2];
    const int* mask = (const int*)d_in[3];
    float* ctx  = (float*)d_out;
    float* prob = (float*)d_out + (size_t)4 * 16 * SEQ * DIM;

    dim3 grid(64 * (SEQ / QBLK));
    dim3 block(THREADS);
    sdpa_mfma5<<<grid, block, 0, stream>>>(Q, K, V, mask, ctx, prob);
}

// Round 8
// 1083.536 us; speedup vs baseline: 3.6669x; 1.1164x over previous
//
#include <hip/hip_runtime.h>
#include <stdint.h>

// B=4,H=16,S=2048,D=64 fp32 SDPA with materialized attn_prob.
// Swapped QK^T MFMA (lane owns one q-row); P via padded-LDS round-trip;
// V via vectorized LDS staging + conflict-free scalar column reads.
// r8: 2-deep QK^T prefetch, PV V-prefetch pipeline, XCD swizzle, VPAD=18.
#define SEQ 2048
#define DIM 64
#define QBLK 16
#define NWAVE 8
#define KPW 256                 // k-columns per wave
#define NCT 16                  // 16-wide tiles per wave (QK^T)
#define NCHUNK 8                // 32-wide PV chunks per wave
#define THREADS 512
#define SCALE 0.125f
#define LOG2E 1.4426950408889634f
#define PSTR 40                 // plds row stride in bf16 (80 B, conflict-free b128)
#define VPAD 18                 // vbuf row stride in bf16 (36 B = 9 dwords -> conflict-free reads)

typedef __attribute__((ext_vector_type(4))) float f32x4;
typedef __attribute__((ext_vector_type(8))) __bf16 bf16x8;

static __device__ __forceinline__ unsigned int bfbits(float x) {
    union { __bf16 b; unsigned short u; } cv; cv.b = (__bf16)x; return (unsigned int)cv.u;
}

struct WaveBuf {
    union {
        __bf16 vbuf[4][32][VPAD];    // 4608 B: V chunk, [nt][k][c] padded
        float  ctx[QBLK * DIM];      // 4096 B: ctx partial (used after PV)
    };
};

struct SharedT {
    WaveBuf sw[NWAVE];
    __bf16 plds[NWAVE][QBLK][PSTR];  // P round-trip, padded stride
    float red_m[QBLK][NWAVE];
    float red_s[QBLK][NWAVE];
};

__global__ __launch_bounds__(THREADS)
void sdpa_mfma6(const float* __restrict__ Q, const float* __restrict__ K,
                const float* __restrict__ V, const int* __restrict__ mask,
                float* __restrict__ ctx_out, float* __restrict__ prob_out) {
    __shared__ SharedT su;

    // XCD-aware swizzle: grid 8192 = 8 XCDs x 1024; give each XCD a contiguous
    // run of q-blocks so one bh's K/V (1 MB) stays resident in its 4 MB L2.
    const int rb   = ((blockIdx.x & 7) << 10) + (blockIdx.x >> 3);
    const int bh   = rb >> 7;
    const int q0   = (rb & 127) * QBLK;
    const int t    = threadIdx.x;
    const int lane = t & 63;
    const int w    = t >> 6;
    const int g    = lane >> 4;          // 0..3
    const int c    = lane & 15;          // lane's q-row (and N-col)

    const size_t bh_off = (size_t)bh * SEQ * DIM;
    const float* Qb = Q + bh_off;
    const float* Kb = K + bh_off;
    const float* Vb = V + bh_off;
    const int*   Mb = mask + (size_t)bh * SEQ * SEQ;
    const int wbase = w * KPW;

    // ---- Q^T B-fragments, from global, kept in regs ----
    bf16x8 qf[2];
    {
        const float* qr = Qb + (size_t)(q0 + c) * DIM + 8 * g;
        #pragma unroll
        for (int h = 0; h < 2; ++h) {
            f32x4 a = *(const f32x4*)(qr + 32 * h);
            f32x4 b = *(const f32x4*)(qr + 32 * h + 4);
            bf16x8 f;
            f[0]=(__bf16)a[0]; f[1]=(__bf16)a[1]; f[2]=(__bf16)a[2]; f[3]=(__bf16)a[3];
            f[4]=(__bf16)b[0]; f[5]=(__bf16)b[1]; f[6]=(__bf16)b[2]; f[7]=(__bf16)b[3];
            qf[h] = f;
        }
    }

    // =============== QK^T, 2-deep pipelined over 16 tiles ===============
    f32x4 sc[NCT];
    f32x4 kraw[2][4];
    int4  mraw[2];
    {   // prologue: tile 0
        const float* kr = Kb + (size_t)(wbase + c) * DIM + 8 * g;
        kraw[0][0] = *(const f32x4*)(kr);
        kraw[0][1] = *(const f32x4*)(kr + 4);
        kraw[0][2] = *(const f32x4*)(kr + 32);
        kraw[0][3] = *(const f32x4*)(kr + 36);
        mraw[0] = *(const int4*)(Mb + (size_t)(q0 + c) * SEQ + wbase + 4 * g);
    }
    #pragma unroll
    for (int ct = 0; ct < NCT; ++ct) {
        const int cur = ct & 1, nxt = cur ^ 1;
        if (ct + 1 < NCT) {   // issue next tile's loads first
            const float* kr = Kb + (size_t)(wbase + (ct + 1) * 16 + c) * DIM + 8 * g;
            kraw[nxt][0] = *(const f32x4*)(kr);
            kraw[nxt][1] = *(const f32x4*)(kr + 4);
            kraw[nxt][2] = *(const f32x4*)(kr + 32);
            kraw[nxt][3] = *(const f32x4*)(kr + 36);
            mraw[nxt] = *(const int4*)(Mb + (size_t)(q0 + c) * SEQ + wbase + (ct + 1) * 16 + 4 * g);
        }
        bf16x8 kf0, kf1;
        {
            f32x4 a = kraw[cur][0], b = kraw[cur][1];
            kf0[0]=(__bf16)a[0]; kf0[1]=(__bf16)a[1]; kf0[2]=(__bf16)a[2]; kf0[3]=(__bf16)a[3];
            kf0[4]=(__bf16)b[0]; kf0[5]=(__bf16)b[1]; kf0[6]=(__bf16)b[2]; kf0[7]=(__bf16)b[3];
            a = kraw[cur][2]; b = kraw[cur][3];
            kf1[0]=(__bf16)a[0]; kf1[1]=(__bf16)a[1]; kf1[2]=(__bf16)a[2]; kf1[3]=(__bf16)a[3];
            kf1[4]=(__bf16)b[0]; kf1[5]=(__bf16)b[1]; kf1[6]=(__bf16)b[2]; kf1[7]=(__bf16)b[3];
        }
        f32x4 acc = {0.f, 0.f, 0.f, 0.f};
        acc = __builtin_amdgcn_mfma_f32_16x16x32_bf16(kf0, qf[0], acc, 0, 0, 0);
        acc = __builtin_amdgcn_mfma_f32_16x16x32_bf16(kf1, qf[1], acc, 0, 0, 0);
        int4 m = mraw[cur];
        f32x4 s;
        s[0] = m.x ? -1e9f : acc[0] * SCALE;
        s[1] = m.y ? -1e9f : acc[1] * SCALE;
        s[2] = m.z ? -1e9f : acc[2] * SCALE;
        s[3] = m.w ? -1e9f : acc[3] * SCALE;
        sc[ct] = s;
    }

    // ---- staging geometry + chunk-0 V prefetch (in flight across softmax barriers) ----
    const int r_st = lane >> 4;
    const int c0   = (lane & 15) * 4;
    const int ntw  = c0 >> 4;
    const int cw   = c0 & 15;
    f32x4 vrawA[4], vrawB[4];
    {
        const float* vsrc = Vb + (size_t)(wbase + r_st) * DIM + c0;
        #pragma unroll
        for (int i = 0; i < 4; ++i) {
            vrawA[i] = *(const f32x4*)(vsrc + (size_t)(4 * i) * DIM);
            vrawB[i] = *(const f32x4*)(vsrc + (size_t)(16 + 4 * i) * DIM);
        }
    }

    // =============== softmax (lane owns row q=c) ===============
    float mx = -3e38f;
    #pragma unroll
    for (int ct = 0; ct < NCT; ++ct)
        mx = fmaxf(mx, fmaxf(fmaxf(sc[ct][0], sc[ct][1]), fmaxf(sc[ct][2], sc[ct][3])));
    mx = fmaxf(mx, __shfl_xor(mx, 16));
    mx = fmaxf(mx, __shfl_xor(mx, 32));
    if (g == 0) su.red_m[c][w] = mx;
    __syncthreads();
    float M = su.red_m[c][0];
    #pragma unroll
    for (int i = 1; i < NWAVE; ++i) M = fmaxf(M, su.red_m[c][i]);

    float sum = 0.f;
    #pragma unroll
    for (int ct = 0; ct < NCT; ++ct) {
        f32x4 s = sc[ct];
        s[0] = exp2f((s[0] - M) * LOG2E);
        s[1] = exp2f((s[1] - M) * LOG2E);
        s[2] = exp2f((s[2] - M) * LOG2E);
        s[3] = exp2f((s[3] - M) * LOG2E);
        sum += (s[0] + s[1]) + (s[2] + s[3]);
        sc[ct] = s;
    }
    sum += __shfl_xor(sum, 16);
    sum += __shfl_xor(sum, 32);
    if (g == 0) su.red_s[c][w] = sum;
    __syncthreads();
    float S = 0.f;
    #pragma unroll
    for (int i = 0; i < NWAVE; ++i) S += su.red_s[c][i];
    const float inv = 1.0f / S;

    // =============== PV + prob write, 2-deep V pipeline, barrier-free per wave ===============
    f32x4 cacc[4];
    #pragma unroll
    for (int nt = 0; nt < 4; ++nt) cacc[nt] = (f32x4){0.f, 0.f, 0.f, 0.f};

    float* prow = prob_out + ((size_t)bh * SEQ + (q0 + c)) * SEQ + wbase;

    #pragma unroll
    for (int cc = 0; cc < NCHUNK; ++cc) {
        // stage the chunk loaded last iteration (ushort2 pairs: 4B-aligned, VPAD=18)
        #pragma unroll
        for (int i = 0; i < 4; ++i) {
            ushort2 lo, hi;
            lo.x = (unsigned short)bfbits(vrawA[i][0]);
            lo.y = (unsigned short)bfbits(vrawA[i][1]);
            hi.x = (unsigned short)bfbits(vrawA[i][2]);
            hi.y = (unsigned short)bfbits(vrawA[i][3]);
            *(ushort2*)&su.sw[w].vbuf[ntw][4 * i + r_st][cw]     = lo;
            *(ushort2*)&su.sw[w].vbuf[ntw][4 * i + r_st][cw + 2] = hi;
        }
        #pragma unroll
        for (int i = 0; i < 4; ++i) {
            ushort2 lo, hi;
            lo.x = (unsigned short)bfbits(vrawB[i][0]);
            lo.y = (unsigned short)bfbits(vrawB[i][1]);
            hi.x = (unsigned short)bfbits(vrawB[i][2]);
            hi.y = (unsigned short)bfbits(vrawB[i][3]);
            *(ushort2*)&su.sw[w].vbuf[ntw][16 + 4 * i + r_st][cw]     = lo;
            *(ushort2*)&su.sw[w].vbuf[ntw][16 + 4 * i + r_st][cw + 2] = hi;
        }

        // issue NEXT chunk's global loads now (in flight under LDS ops + MFMA)
        if (cc + 1 < NCHUNK) {
            const float* vsrc = Vb + (size_t)(wbase + (cc + 1) * 32 + r_st) * DIM + c0;
            #pragma unroll
            for (int i = 0; i < 4; ++i) {
                vrawA[i] = *(const f32x4*)(vsrc + (size_t)(4 * i) * DIM);
                vrawB[i] = *(const f32x4*)(vsrc + (size_t)(16 + 4 * i) * DIM);
            }
        }

        // prob normalize + write (streaming store overlaps)
        f32x4 p0 = sc[2 * cc], p1 = sc[2 * cc + 1];
        p0[0]*=inv; p0[1]*=inv; p0[2]*=inv; p0[3]*=inv;
        p1[0]*=inv; p1[1]*=inv; p1[2]*=inv; p1[3]*=inv;
        *(f32x4*)(prow + 32 * cc + 4 * g)      = p0;
        *(f32x4*)(prow + 32 * cc + 16 + 4 * g) = p1;

        // P -> padded LDS round-trip, then b128 A-frag read
        {
            ushort4 pk;
            pk.x = (unsigned short)bfbits(p0[0]);
            pk.y = (unsigned short)bfbits(p0[1]);
            pk.z = (unsigned short)bfbits(p0[2]);
            pk.w = (unsigned short)bfbits(p0[3]);
            *(ushort4*)&su.plds[w][c][4 * g] = pk;
            pk.x = (unsigned short)bfbits(p1[0]);
            pk.y = (unsigned short)bfbits(p1[1]);
            pk.z = (unsigned short)bfbits(p1[2]);
            pk.w = (unsigned short)bfbits(p1[3]);
            *(ushort4*)&su.plds[w][c][16 + 4 * g] = pk;
        }
        bf16x8 pf = *(const bf16x8*)&su.plds[w][c][8 * g];

        // B-frags: conflict-free scalar column reads (bank = 8g + c/2 + 9j mod 32)
        bf16x8 vfr[4];
        #pragma unroll
        for (int nt = 0; nt < 4; ++nt) {
            bf16x8 f;
            #pragma unroll
            for (int j = 0; j < 8; ++j)
                f[j] = su.sw[w].vbuf[nt][8 * g + j][c];
            vfr[nt] = f;
        }

        __builtin_amdgcn_s_setprio(1);
        #pragma unroll
        for (int nt = 0; nt < 4; ++nt)
            cacc[nt] = __builtin_amdgcn_mfma_f32_16x16x32_bf16(pf, vfr[nt], cacc[nt], 0, 0, 0);
        __builtin_amdgcn_s_setprio(0);
    }

    // =============== ctx partials (own region overlays own vbuf) + reduce ===============
    #pragma unroll
    for (int nt = 0; nt < 4; ++nt)
        #pragma unroll
        for (int jr = 0; jr < 4; ++jr)
            su.sw[w].ctx[(4 * g + jr) * DIM + nt * 16 + c] = cacc[nt][jr];
    __syncthreads();
    {
        int e = t * 2;
        float2 a = make_float2(0.f, 0.f);
        #pragma unroll
        for (int i = 0; i < NWAVE; ++i) {
            float2 v = *(const float2*)&su.sw[i].ctx[e];
            a.x += v.x; a.y += v.y;
        }
        *(float2*)(ctx_out + ((size_t)bh * SEQ + q0) * DIM + e) = a;
    }
}

extern "C" void kernel_launch(void* const* d_in, const int* in_sizes, int n_in,
                              void* d_out, int out_size, void* d_ws, size_t ws_size,
                              hipStream_t stream) {
    const float* Q = (const float*)d_in[0];
    const float* K = (const float*)d_in[1];
    const float* V = (const float*)d_in[2];
    const int* mask = (const int*)d_in[3];
    float* ctx  = (float*)d_out;
    float* prob = (float*)d_out + (size_t)4 * 16 * SEQ * DIM;

    dim3 grid(64 * (SEQ / QBLK));   // 8192, divisible by 8 XCDs
    dim3 block(THREADS);
    sdpa_mfma6<<<grid, block, 0, stream>>>(Q, K, V, mask, ctx, prob);
}

// Round 9
// 1059.966 us; speedup vs baseline: 3.7485x; 1.0222x over previous
//
#include <hip/hip_runtime.h>
#include <stdint.h>

// B=4,H=16,S=2048,D=64 fp32 SDPA with materialized attn_prob.
// Swapped QK^T MFMA (lane owns one q-row). r9: packed-bf16 scores (reg diet for
// 2 blocks/CU), unnormalized-P PV with epilogue row-scale, nt-stride pad.
#define SEQ 2048
#define DIM 64
#define QBLK 16
#define NWAVE 8
#define KPW 256                 // k-columns per wave
#define NCT 16                  // 16-wide tiles per wave (QK^T)
#define NCHUNK 8                // 32-wide PV chunks per wave
#define THREADS 512
#define SCALE 0.125f
#define LOG2E 1.4426950408889634f
#define PSTR 40                 // plds row stride in bf16 (80 B, 2-way-free b128)
#define VPAD 18                 // vbuf row stride in bf16 (36 B)
#define NTSTR (32*VPAD + 8)     // 584 bf16 = 1168 B == 4 mod 32 dwords: write-bank spread

typedef __attribute__((ext_vector_type(4))) float f32x4;
typedef __attribute__((ext_vector_type(8))) __bf16 bf16x8;

static __device__ __forceinline__ unsigned bfbits(float x) {
    union { __bf16 b; unsigned short u; } cv; cv.b = (__bf16)x; return (unsigned)cv.u;
}
static __device__ __forceinline__ float lo16(unsigned u) { return __uint_as_float(u << 16); }
static __device__ __forceinline__ float hi16(unsigned u) { return __uint_as_float(u & 0xffff0000u); }

struct WaveBuf {
    union {
        __bf16 vbuf[4 * NTSTR];      // 4672 B: V chunk, [nt][k][c] padded + nt-pad
        float  ctx[QBLK * DIM];      // 4096 B: ctx partial (used after PV)
    };
};
struct SharedT {
    WaveBuf sw[NWAVE];
    __bf16 plds[NWAVE][QBLK][PSTR];
    float red_m[QBLK][NWAVE];
    float red_s[QBLK][NWAVE];
};

__global__ __launch_bounds__(THREADS, 4)   // force <=128 combined V+A regs -> 2 blocks/CU
void sdpa_mfma7(const float* __restrict__ Q, const float* __restrict__ K,
                const float* __restrict__ V, const int* __restrict__ mask,
                float* __restrict__ ctx_out, float* __restrict__ prob_out) {
    __shared__ SharedT su;

    // XCD-aware swizzle: 8192 = 8 XCDs x 1024 contiguous q-blocks (8 bh per XCD).
    const int rb   = ((blockIdx.x & 7) << 10) + (blockIdx.x >> 3);
    const int bh   = rb >> 7;
    const int q0   = (rb & 127) * QBLK;
    const int t    = threadIdx.x;
    const int lane = t & 63;
    const int w    = t >> 6;
    const int g    = lane >> 4;          // 0..3
    const int c    = lane & 15;          // lane's q-row (and N-col)

    const size_t bh_off = (size_t)bh * SEQ * DIM;
    const float* Qb = Q + bh_off;
    const float* Kb = K + bh_off;
    const float* Vb = V + bh_off;
    const int*   Mb = mask + (size_t)bh * SEQ * SEQ;
    const int wbase = w * KPW;

    // ---- Q^T B-fragments, from global, kept in regs ----
    bf16x8 qf[2];
    {
        const float* qr = Qb + (size_t)(q0 + c) * DIM + 8 * g;
        #pragma unroll
        for (int h = 0; h < 2; ++h) {
            f32x4 a = *(const f32x4*)(qr + 32 * h);
            f32x4 b = *(const f32x4*)(qr + 32 * h + 4);
            bf16x8 f;
            f[0]=(__bf16)a[0]; f[1]=(__bf16)a[1]; f[2]=(__bf16)a[2]; f[3]=(__bf16)a[3];
            f[4]=(__bf16)b[0]; f[5]=(__bf16)b[1]; f[6]=(__bf16)b[2]; f[7]=(__bf16)b[3];
            qf[h] = f;
        }
    }

    // =============== QK^T, 2-deep pipelined; scores packed bf16x2 ===============
    unsigned sc_pk[2 * NCT];            // 64 scores as 32 packed pairs
    f32x4 kraw[2][4];
    int4  mraw[2];
    {   // prologue: tile 0
        const float* kr = Kb + (size_t)(wbase + c) * DIM + 8 * g;
        kraw[0][0] = *(const f32x4*)(kr);
        kraw[0][1] = *(const f32x4*)(kr + 4);
        kraw[0][2] = *(const f32x4*)(kr + 32);
        kraw[0][3] = *(const f32x4*)(kr + 36);
        mraw[0] = *(const int4*)(Mb + (size_t)(q0 + c) * SEQ + wbase + 4 * g);
    }
    #pragma unroll
    for (int ct = 0; ct < NCT; ++ct) {
        const int cur = ct & 1, nxt = cur ^ 1;
        if (ct + 1 < NCT) {
            const float* kr = Kb + (size_t)(wbase + (ct + 1) * 16 + c) * DIM + 8 * g;
            kraw[nxt][0] = *(const f32x4*)(kr);
            kraw[nxt][1] = *(const f32x4*)(kr + 4);
            kraw[nxt][2] = *(const f32x4*)(kr + 32);
            kraw[nxt][3] = *(const f32x4*)(kr + 36);
            mraw[nxt] = *(const int4*)(Mb + (size_t)(q0 + c) * SEQ + wbase + (ct + 1) * 16 + 4 * g);
        }
        bf16x8 kf0, kf1;
        {
            f32x4 a = kraw[cur][0], b = kraw[cur][1];
            kf0[0]=(__bf16)a[0]; kf0[1]=(__bf16)a[1]; kf0[2]=(__bf16)a[2]; kf0[3]=(__bf16)a[3];
            kf0[4]=(__bf16)b[0]; kf0[5]=(__bf16)b[1]; kf0[6]=(__bf16)b[2]; kf0[7]=(__bf16)b[3];
            a = kraw[cur][2]; b = kraw[cur][3];
            kf1[0]=(__bf16)a[0]; kf1[1]=(__bf16)a[1]; kf1[2]=(__bf16)a[2]; kf1[3]=(__bf16)a[3];
            kf1[4]=(__bf16)b[0]; kf1[5]=(__bf16)b[1]; kf1[6]=(__bf16)b[2]; kf1[7]=(__bf16)b[3];
        }
        f32x4 acc = {0.f, 0.f, 0.f, 0.f};
        acc = __builtin_amdgcn_mfma_f32_16x16x32_bf16(kf0, qf[0], acc, 0, 0, 0);
        acc = __builtin_amdgcn_mfma_f32_16x16x32_bf16(kf1, qf[1], acc, 0, 0, 0);
        int4 m = mraw[cur];
        float s0 = m.x ? -1e9f : acc[0] * SCALE;
        float s1 = m.y ? -1e9f : acc[1] * SCALE;
        float s2 = m.z ? -1e9f : acc[2] * SCALE;
        float s3 = m.w ? -1e9f : acc[3] * SCALE;
        sc_pk[2 * ct]     = bfbits(s0) | (bfbits(s1) << 16);
        sc_pk[2 * ct + 1] = bfbits(s2) | (bfbits(s3) << 16);
    }

    // ---- staging geometry + chunk-0 V prefetch (in flight across softmax) ----
    const int r_st = lane >> 4;
    const int cw   = (4 * c) & 15;
    const int ntw  = c >> 2;
    f32x4 vrawA[4], vrawB[4];
    {
        const float* vsrc = Vb + (size_t)(wbase + r_st) * DIM + 4 * c;
        #pragma unroll
        for (int i = 0; i < 4; ++i) {
            vrawA[i] = *(const f32x4*)(vsrc + (size_t)(4 * i) * DIM);
            vrawB[i] = *(const f32x4*)(vsrc + (size_t)(16 + 4 * i) * DIM);
        }
    }

    // =============== softmax (lane owns row q=c); e kept UNnormalized ===============
    float mx = -3e38f;
    #pragma unroll
    for (int i = 0; i < 2 * NCT; ++i)
        mx = fmaxf(mx, fmaxf(lo16(sc_pk[i]), hi16(sc_pk[i])));
    mx = fmaxf(mx, __shfl_xor(mx, 16));
    mx = fmaxf(mx, __shfl_xor(mx, 32));
    if (g == 0) su.red_m[c][w] = mx;
    __syncthreads();
    float M = su.red_m[c][0];
    #pragma unroll
    for (int i = 1; i < NWAVE; ++i) M = fmaxf(M, su.red_m[c][i]);

    float sum = 0.f;
    #pragma unroll
    for (int i = 0; i < 2 * NCT; ++i) {
        float e0 = exp2f((lo16(sc_pk[i]) - M) * LOG2E);
        float e1 = exp2f((hi16(sc_pk[i]) - M) * LOG2E);
        sum += e0 + e1;
        sc_pk[i] = bfbits(e0) | (bfbits(e1) << 16);   // raw e, bf16-packed
    }
    sum += __shfl_xor(sum, 16);
    sum += __shfl_xor(sum, 32);
    if (g == 0) su.red_s[c][w] = sum;
    __syncthreads();
    float S = 0.f;
    #pragma unroll
    for (int i = 0; i < NWAVE; ++i) S += su.red_s[c][i];
    const float inv = 1.0f / S;
    // per-output-row inverse sums for the epilogue (PV rows are q=4g+jr)
    float invr[4];
    #pragma unroll
    for (int jr = 0; jr < 4; ++jr) invr[jr] = __shfl(inv, 4 * g + jr);

    // =============== PV + prob write, 2-deep V pipeline, barrier-free per wave ===============
    f32x4 cacc[4];
    #pragma unroll
    for (int nt = 0; nt < 4; ++nt) cacc[nt] = (f32x4){0.f, 0.f, 0.f, 0.f};

    float* prow = prob_out + ((size_t)bh * SEQ + (q0 + c)) * SEQ + wbase;
    __bf16* vbufW = su.sw[w].vbuf;

    #pragma unroll
    for (int cc = 0; cc < NCHUNK; ++cc) {
        // stage the chunk loaded last iteration
        #pragma unroll
        for (int i = 0; i < 4; ++i) {
            ushort2 lo_, hi_;
            lo_.x = (unsigned short)bfbits(vrawA[i][0]);
            lo_.y = (unsigned short)bfbits(vrawA[i][1]);
            hi_.x = (unsigned short)bfbits(vrawA[i][2]);
            hi_.y = (unsigned short)bfbits(vrawA[i][3]);
            __bf16* p = &vbufW[ntw * NTSTR + (4 * i + r_st) * VPAD + cw];
            *(ushort2*)p = lo_;
            *(ushort2*)(p + 2) = hi_;
        }
        #pragma unroll
        for (int i = 0; i < 4; ++i) {
            ushort2 lo_, hi_;
            lo_.x = (unsigned short)bfbits(vrawB[i][0]);
            lo_.y = (unsigned short)bfbits(vrawB[i][1]);
            hi_.x = (unsigned short)bfbits(vrawB[i][2]);
            hi_.y = (unsigned short)bfbits(vrawB[i][3]);
            __bf16* p = &vbufW[ntw * NTSTR + (16 + 4 * i + r_st) * VPAD + cw];
            *(ushort2*)p = lo_;
            *(ushort2*)(p + 2) = hi_;
        }

        // issue NEXT chunk's global loads now
        if (cc + 1 < NCHUNK) {
            const float* vsrc = Vb + (size_t)(wbase + (cc + 1) * 32 + r_st) * DIM + 4 * c;
            #pragma unroll
            for (int i = 0; i < 4; ++i) {
                vrawA[i] = *(const f32x4*)(vsrc + (size_t)(4 * i) * DIM);
                vrawB[i] = *(const f32x4*)(vsrc + (size_t)(16 + 4 * i) * DIM);
            }
        }

        // prob write (normalized f32), plds write (raw bf16 e, already packed)
        unsigned pkA0 = sc_pk[4 * cc], pkA1 = sc_pk[4 * cc + 1];
        unsigned pkB0 = sc_pk[4 * cc + 2], pkB1 = sc_pk[4 * cc + 3];
        {
            f32x4 pn0 = { lo16(pkA0) * inv, hi16(pkA0) * inv, lo16(pkA1) * inv, hi16(pkA1) * inv };
            f32x4 pn1 = { lo16(pkB0) * inv, hi16(pkB0) * inv, lo16(pkB1) * inv, hi16(pkB1) * inv };
            *(f32x4*)(prow + 32 * cc + 4 * g)      = pn0;
            *(f32x4*)(prow + 32 * cc + 16 + 4 * g) = pn1;
        }
        {
            uint2 ua; ua.x = pkA0; ua.y = pkA1;
            uint2 ub; ub.x = pkB0; ub.y = pkB1;
            *(uint2*)&su.plds[w][c][4 * g]      = ua;
            *(uint2*)&su.plds[w][c][16 + 4 * g] = ub;
        }
        bf16x8 pf = *(const bf16x8*)&su.plds[w][c][8 * g];

        // B-frags: conflict-free scalar column reads
        bf16x8 vfr[4];
        #pragma unroll
        for (int nt = 0; nt < 4; ++nt) {
            bf16x8 f;
            #pragma unroll
            for (int j = 0; j < 8; ++j)
                f[j] = vbufW[nt * NTSTR + (8 * g + j) * VPAD + c];
            vfr[nt] = f;
        }

        __builtin_amdgcn_s_setprio(1);
        #pragma unroll
        for (int nt = 0; nt < 4; ++nt)
            cacc[nt] = __builtin_amdgcn_mfma_f32_16x16x32_bf16(pf, vfr[nt], cacc[nt], 0, 0, 0);
        __builtin_amdgcn_s_setprio(0);
    }

    // =============== ctx partials (scaled by per-row inv) + cross-wave reduce ===============
    #pragma unroll
    for (int nt = 0; nt < 4; ++nt)
        #pragma unroll
        for (int jr = 0; jr < 4; ++jr)
            su.sw[w].ctx[(4 * g + jr) * DIM + nt * 16 + c] = cacc[nt][jr] * invr[jr];
    __syncthreads();
    {
        int e = t * 2;
        float2 a = make_float2(0.f, 0.f);
        #pragma unroll
        for (int i = 0; i < NWAVE; ++i) {
            float2 v = *(const float2*)&su.sw[i].ctx[e];
            a.x += v.x; a.y += v.y;
        }
        *(float2*)(ctx_out + ((size_t)bh * SEQ + q0) * DIM + e) = a;
    }
}

extern "C" void kernel_launch(void* const* d_in, const int* in_sizes, int n_in,
                              void* d_out, int out_size, void* d_ws, size_t ws_size,
                              hipStream_t stream) {
    const float* Q = (const float*)d_in[0];
    const float* K = (const float*)d_in[1];
    const float* V = (const float*)d_in[2];
    const int* mask = (const int*)d_in[3];
    float* ctx  = (float*)d_out;
    float* prob = (float*)d_out + (size_t)4 * 16 * SEQ * DIM;

    dim3 grid(64 * (SEQ / QBLK));   // 8192, divisible by 8 XCDs
    dim3 block(THREADS);
    sdpa_mfma7<<<grid, block, 0, stream>>>(Q, K, V, mask, ctx, prob);
}